// Round 1
// 285.477 us; speedup vs baseline: 1.1862x; 1.1862x over previous
//
#include <hip/hip_runtime.h>

// Problem: B=2, T=4096, C=768, H=12, HD=64. Inputs f32, OUTPUT f32.
// R11: swapped QK^T (S^T = K·Q^T) keeps P in-register. v_cvt_pk_bf16_f32
// packs P directly into the PV A-fragment; the implied k-slot permutation
// is applied equally to the V B-fragment (two b64 LDS reads 32B apart).
// Eliminates the Ps LDS round-trip (32 ds_write_b16 + 4 ds_read_b128 +
// ~112 f2bf VALU per tile) that made attn_chunk VALU-bound
// (r10 counters: VALUBusy 43.6% vs MfmaUtil 14.8%, 8.1M bank conflicts).
// LDS 36.9 -> 18.4 KB. r10 structure otherwise retained: no-max softmax,
// uniform split-K chunking (1920 blocks), V pre-transposed (d,t),
// Q pre-scaled by 0.125*log2e.

typedef unsigned short u16;
typedef unsigned int u32;
using bf16x8 = __attribute__((ext_vector_type(8))) short;
using f32x4  = __attribute__((ext_vector_type(4))) float;

__device__ __forceinline__ float bf2f(u16 u) {
  return __uint_as_float(((u32)u) << 16);
}
__device__ __forceinline__ u16 f2bf(float f) {
  u32 u = __float_as_uint(f);
  u += 0x7fffu + ((u >> 16) & 1u);   // RNE
  return (u16)(u >> 16);
}
__device__ __forceinline__ u32 cvtpk(float lo, float hi) {
  u32 r;
  asm("v_cvt_pk_bf16_f32 %0, %1, %2" : "=v"(r) : "v"(lo), "v"(hi));
  return r;
}

__global__ void fill_sentinel_f32(float* __restrict__ out, int n, float v) {
  const int i0 = blockIdx.x * blockDim.x + threadIdx.x;
  const int stride = gridDim.x * blockDim.x;
  for (int i = i0; i < n; i += stride) out[i] = v;
}

// ------------------------------------------------------------ canonicalize
__global__ void convert_f32_bf16(const float* __restrict__ src, u16* __restrict__ dst,
                                 int n) {
  const int i0 = blockIdx.x * blockDim.x + threadIdx.x;
  const int stride = gridDim.x * blockDim.x;
  for (int i = i0; i < n; i += stride) dst[i] = f2bf(src[i]);
}

__global__ void transpose_f32_bf16(const float* __restrict__ in, u16* __restrict__ out,
                                   int R, int C) {
  __shared__ u16 tile[32][33];
  const int c0 = blockIdx.x * 32, r0 = blockIdx.y * 32;
  const int tx = threadIdx.x & 31, ty = threadIdx.x >> 5;
#pragma unroll
  for (int i = 0; i < 32; i += 8)
    tile[ty + i][tx] = f2bf(in[(size_t)(r0 + ty + i) * C + c0 + tx]);
  __syncthreads();
#pragma unroll
  for (int i = 0; i < 32; i += 8)
    out[(size_t)(c0 + ty + i) * R + r0 + tx] = tile[tx][ty + i];
}

// ---------------------------------------------------------------- GEMM (MFMA)
#define LDT 72
#define QSCALE 0.18033688011112f   // 0.125 * log2(e)

__device__ __forceinline__ void stage_tile(u16* lds, const u16* g, int ld, int tid) {
#pragma unroll
  for (int i = 0; i < 4; ++i) {
    const int idx = i * 256 + tid;
    const int r = idx >> 3, c = (idx & 7) * 8;
    *(uint4*)&lds[r * LDT + c] = *(const uint4*)&g[(size_t)r * ld + c];
  }
}

template <int MODE>
__global__ __launch_bounds__(256, 2)
void gemm128(const u16* __restrict__ A, const u16* __restrict__ Bt,
             const u16* __restrict__ bias, void* __restrict__ O0v,
             u16* __restrict__ O1, u16* __restrict__ O2, int Kd) {
  __shared__ __align__(16) u16 As[128 * LDT];
  __shared__ __align__(16) u16 Bs[128 * LDT];
  const int tid = threadIdx.x;
  const int lane = tid & 63, wave = tid >> 6;
  const int wm = wave >> 1, wn = wave & 1;
  const int l16 = lane & 15, quad = lane >> 4;

  const u16* Ag = A + (size_t)blockIdx.x * 128 * Kd;
  const u16* Bg = Bt + (size_t)blockIdx.y * 128 * Kd;

  f32x4 acc[4][4] = {};
  for (int kt = 0; kt < Kd; kt += 64) {
    stage_tile(As, Ag + kt, Kd, tid);
    stage_tile(Bs, Bg + kt, Kd, tid);
    __syncthreads();
#pragma unroll
    for (int s = 0; s < 2; ++s) {
      bf16x8 af[4], bfr[4];
#pragma unroll
      for (int i = 0; i < 4; ++i) {
        const int m = wm * 64 + i * 16 + l16;
        af[i] = *(const bf16x8*)&As[m * LDT + (s * 4 + quad) * 8];
        const int n = wn * 64 + i * 16 + l16;
        bfr[i] = *(const bf16x8*)&Bs[n * LDT + (s * 4 + quad) * 8];
      }
#pragma unroll
      for (int i = 0; i < 4; ++i)
#pragma unroll
        for (int j = 0; j < 4; ++j)
          acc[i][j] = __builtin_amdgcn_mfma_f32_16x16x32_bf16(af[i], bfr[j],
                                                              acc[i][j], 0, 0, 0);
    }
    __syncthreads();
  }

#pragma unroll
  for (int i = 0; i < 4; ++i) {
    const int mbase = blockIdx.x * 128 + wm * 64 + i * 16 + quad * 4;
#pragma unroll
    for (int j = 0; j < 4; ++j) {
      const int n = blockIdx.y * 128 + wn * 64 + j * 16 + l16;
      const float bv = bf2f(bias[n]);
#pragma unroll
      for (int r = 0; r < 4; ++r) {
        const int m = mbase + r;
        float ov = acc[i][j][r] + bv;
        if (MODE == 0) {
          const int b = m >> 12, t = m & 4095;
          const int which = n / 768;
          const int c = n - which * 768;
          const int h = c >> 6, d = c & 63;
          const size_t bh = (size_t)b * 12 + h;
          if (which == 0) {
            ((u16*)O0v)[((bh * 4096 + t) << 6) + d] = f2bf(ov * QSCALE);
          } else if (which == 1) {
            O1[((bh * 4096 + t) << 6) + d] = f2bf(ov);
          } else {
            O2[((bh << 6) + d) * 4096 + t] = f2bf(ov);   // V transposed (d,t)
          }
        } else {
          ((float*)O0v)[(size_t)m * 768 + n] = ov;
        }
      }
    }
  }
}

// ---------------------------------------------------------------- attention
// Grid: 24 bh x 80 chunks = 1920 blocks. Chunk = (q-tile qt, j-th run of 16
// KV tiles). nc(qt)=ceil((qt+1)/8): qt<8 single-chunk -> direct Y write;
// else bf16 partial O + f32 partial l (additive; no-max softmax).
//
// R11 inner structure: S^T = mfma(K-rows, Q-rows) so lane (l16,quad) owns
// P[t = nt*16+quad*4+r][q = rt*16+l16]. P packed in-register via cvt_pk;
// PV uses k-slot permutation pi(quad,s2,j) = (2*s2+(j>>2))*16+quad*4+(j&3)
// on BOTH operands (A from packed P words, B from two b64 Vs reads).
__global__ __launch_bounds__(256, 4)
void attn_chunk(const u16* __restrict__ Q, const u16* __restrict__ K,
                const u16* __restrict__ Vt, u16* __restrict__ Y,
                u16* __restrict__ part_o, float* __restrict__ part_l) {
  const int idx = blockIdx.x;
  const int bh = idx % 24;               // XCD-pinned
  const int cid = 79 - (idx / 24);       // big q-tiles dispatch first
  int qt = 0, base = 0, nc = 1;
  for (int q = 0; q < 32; ++q) {         // decode cid -> (qt, j)
    const int c = (q >> 3) + 1;
    if (cid < base + c) { qt = q; nc = c; break; }
    base += c;
  }
  const int j = cid - base;
  const int Nt = 2 * qt + 2;
  const int kbeg = j * 16;
  const int kend = (kbeg + 16 < Nt) ? kbeg + 16 : Nt;
  const int q0 = qt * 128;
  const int b = bh / 12, h = bh % 12;
  const size_t ho = (size_t)bh * 4096 * 64;
  const u16* Qg = Q + ho + (size_t)q0 * 64;
  const u16* Kg = K + ho;
  const u16* Vg = Vt + ho;               // (64, 4096)

  __shared__ __align__(16) u16 Ks[64 * LDT];
  __shared__ __align__(16) u16 Vs[64 * LDT];

  const int tid = threadIdx.x;
  const int lane = tid & 63, wave = tid >> 6;
  const int l16 = lane & 15, quad = lane >> 4;

  bf16x8 qf[2][2];
#pragma unroll
  for (int rt = 0; rt < 2; ++rt)
#pragma unroll
    for (int s = 0; s < 2; ++s)
      qf[rt][s] = *(const bf16x8*)&Qg[(wave * 32 + rt * 16 + l16) * 64 + s * 32 + quad * 8];

  float lsum[2] = {};
  f32x4 o[2][4] = {};

  for (int kt2 = kbeg; kt2 < kend; ++kt2) {
    const int t0 = kt2 * 64;
    __syncthreads();
    {
      int c = tid;
      *(uint4*)&Ks[(c >> 3) * LDT + (c & 7) * 8] =
          *(const uint4*)&Kg[(size_t)(t0 + (c >> 3)) * 64 + (c & 7) * 8];
      c = tid + 256;
      *(uint4*)&Ks[(c >> 3) * LDT + (c & 7) * 8] =
          *(const uint4*)&Kg[(size_t)(t0 + (c >> 3)) * 64 + (c & 7) * 8];
      c = tid;
      *(uint4*)&Vs[(c >> 3) * LDT + (c & 7) * 8] =
          *(const uint4*)&Vg[(size_t)(c >> 3) * 4096 + t0 + (c & 7) * 8];
      c = tid + 256;
      *(uint4*)&Vs[(c >> 3) * LDT + (c & 7) * 8] =
          *(const uint4*)&Vg[(size_t)(c >> 3) * 4096 + t0 + (c & 7) * 8];
    }
    __syncthreads();

    // ---- S^T = K Q^T : 16 MFMA. sc[nt][rt]: row=t (quad*4+r), col=q (l16)
    f32x4 sc[4][2] = {};
#pragma unroll
    for (int s = 0; s < 2; ++s) {
      bf16x8 kf[4];
#pragma unroll
      for (int nt = 0; nt < 4; ++nt)
        kf[nt] = *(const bf16x8*)&Ks[(nt * 16 + l16) * LDT + s * 32 + quad * 8];
#pragma unroll
      for (int nt = 0; nt < 4; ++nt)
#pragma unroll
        for (int rt = 0; rt < 2; ++rt)
          sc[nt][rt] = __builtin_amdgcn_mfma_f32_16x16x32_bf16(kf[nt], qf[rt][s],
                                                               sc[nt][rt], 0, 0, 0);
    }

    // ---- no-max softmax + in-register bf16 pack ----
    u32 pw[4][2][2];
#pragma unroll
    for (int rt = 0; rt < 2; ++rt) {
      const int rowb = q0 + wave * 32 + rt * 16;
      if (t0 + 63 <= rowb) {               // tile fully below diagonal
#pragma unroll
        for (int nt = 0; nt < 4; ++nt) {
          f32x4 p;
#pragma unroll
          for (int r = 0; r < 4; ++r) {
            p[r] = __builtin_amdgcn_exp2f(sc[nt][rt][r]);
            lsum[rt] += p[r];
          }
          pw[nt][rt][0] = cvtpk(p[0], p[1]);
          pw[nt][rt][1] = cvtpk(p[2], p[3]);
        }
      } else {
        const int qrow = rowb + l16;
#pragma unroll
        for (int nt = 0; nt < 4; ++nt) {
          f32x4 p;
#pragma unroll
          for (int r = 0; r < 4; ++r) {
            float pv = __builtin_amdgcn_exp2f(sc[nt][rt][r]);
            if (t0 + nt * 16 + quad * 4 + r > qrow) pv = 0.f;
            p[r] = pv;
            lsum[rt] += pv;
          }
          pw[nt][rt][0] = cvtpk(p[0], p[1]);
          pw[nt][rt][1] = cvtpk(p[2], p[3]);
        }
      }
    }

    // ---- O += P V : 16 MFMA, permuted k-slots on both operands ----
#pragma unroll
    for (int s2 = 0; s2 < 2; ++s2) {
      bf16x8 vf[4];
#pragma unroll
      for (int dt = 0; dt < 4; ++dt) {
        const u16* vp = &Vs[(dt * 16 + l16) * LDT + s2 * 32 + quad * 4];
        union { uint2 h[2]; bf16x8 v; } uv;
        uv.h[0] = *(const uint2*)vp;          // t' = 32*s2 + quad*4 + 0..3
        uv.h[1] = *(const uint2*)(vp + 16);   // t' = 32*s2 + 16 + quad*4 + 0..3
        vf[dt] = uv.v;
      }
#pragma unroll
      for (int rt = 0; rt < 2; ++rt) {
        union { u32 w[4]; bf16x8 v; } up;
        up.w[0] = pw[2 * s2][rt][0];
        up.w[1] = pw[2 * s2][rt][1];
        up.w[2] = pw[2 * s2 + 1][rt][0];
        up.w[3] = pw[2 * s2 + 1][rt][1];
#pragma unroll
        for (int dt = 0; dt < 4; ++dt)
          o[rt][dt] = __builtin_amdgcn_mfma_f32_16x16x32_bf16(up.v, vf[dt],
                                                              o[rt][dt], 0, 0, 0);
      }
    }
  }

  // ---- l reduction: sum across the 4 quads (t-axis), then row-broadcast ----
  float red[2];
#pragma unroll
  for (int rt = 0; rt < 2; ++rt) {
    float rs = lsum[rt];
    rs += __shfl_xor(rs, 16);
    rs += __shfl_xor(rs, 32);
    red[rt] = rs;                          // total for q-row l16 (any quad)
  }

  if (nc == 1) {
    // direct: Y (b, t, h*64+d) bf16
#pragma unroll
    for (int rt = 0; rt < 2; ++rt)
#pragma unroll
      for (int r = 0; r < 4; ++r) {
        const float inv = 1.f / __shfl(red[rt], quad * 4 + r);
        const int t = q0 + wave * 32 + rt * 16 + quad * 4 + r;
#pragma unroll
        for (int dt = 0; dt < 4; ++dt)
          Y[((size_t)b * 4096 + t) * 768 + h * 64 + dt * 16 + l16] =
              f2bf(o[rt][dt][r] * inv);
      }
  } else {
    const int pslot = bh * 72 + (cid - 8);     // cids 8..79 are partial chunks
    u16* po = part_o + (size_t)pslot * 8192;   // [row 0..127][d 0..63]
    float* pl = part_l + pslot * 128;
#pragma unroll
    for (int rt = 0; rt < 2; ++rt)
#pragma unroll
      for (int r = 0; r < 4; ++r) {
        const float rs = __shfl(red[rt], quad * 4 + r);
        const int row = wave * 32 + rt * 16 + quad * 4 + r;
#pragma unroll
        for (int dt = 0; dt < 4; ++dt)
          po[row * 64 + dt * 16 + l16] = f2bf(o[rt][dt][r]);
        if (l16 == 0) pl[row] = rs;
      }
  }
}

// Combine partial chunks for qt >= 8.  Grid (24 bh, 24 qt-8).
__global__ __launch_bounds__(256, 8)
void attn_combine(const u16* __restrict__ part_o, const float* __restrict__ part_l,
                  u16* __restrict__ Y) {
  const int bh = blockIdx.x, qt = 8 + blockIdx.y;
  const int g = qt >> 3, i = qt & 7;
  const int nc = g + 1;
  const int base = 4 * g * (g + 1) + i * (g + 1);
  const int slot0 = bh * 72 + base - 8;
  const int b = bh / 12, h = bh % 12;
  const int q0 = qt * 128;
  for (int e = threadIdx.x; e < 8192; e += 256) {
    const int row = e >> 6, d = e & 63;
    float Os = 0.f, ls = 0.f;
    for (int c = 0; c < nc; ++c) {
      Os += bf2f(part_o[(size_t)(slot0 + c) * 8192 + e]);
      ls += part_l[(slot0 + c) * 128 + row];
    }
    Y[((size_t)b * 4096 + q0 + row) * 768 + h * 64 + d] = f2bf(Os / ls);
  }
}

// ---------------------------------------------------------------- launch
extern "C" void kernel_launch(void* const* d_in, const int* in_sizes, int n_in,
                              void* d_out, int out_size, void* d_ws, size_t ws_size,
                              hipStream_t stream) {
  (void)in_sizes; (void)n_in;
  const float* x      = (const float*)d_in[0];
  const float* w_attn = (const float*)d_in[1];
  const float* b_attn = (const float*)d_in[2];
  const float* w_proj = (const float*)d_in[3];
  const float* b_proj = (const float*)d_in[4];
  float* out = (float*)d_out;

  char* ws = (char*)d_ws;
  size_t off = 0;
  auto alloc = [&](size_t bytes) -> void* {
    void* p = ws + off;
    off += (bytes + 255) & ~(size_t)255;
    return p;
  };
  u16* xb  = (u16*)alloc((size_t)8192 * 768 * 2);
  u16* WtA = (u16*)alloc((size_t)2304 * 768 * 2);
  u16* WtP = (u16*)alloc((size_t)768 * 768 * 2);
  u16* ba  = (u16*)alloc(2304 * 2);
  u16* bp  = (u16*)alloc(768 * 2);
  u16* Q   = (u16*)alloc((size_t)6291456 * 2);   // (B,H,T,64), pre-scaled
  u16* Kp  = (u16*)alloc((size_t)6291456 * 2);   // (B,H,T,64)
  u16* Vt  = (u16*)alloc((size_t)6291456 * 2);   // (B,H,64,T)
  u16* Y   = (u16*)alloc((size_t)6291456 * 2);
  u16* part_o  = (u16*)alloc((size_t)24 * 72 * 8192 * 2);   // 28.3 MB
  float* part_l = (float*)alloc((size_t)24 * 72 * 128 * 4);

  if (ws_size < off) {   // decodable sentinel: absmax ~= 100 + ws_MB
    fill_sentinel_f32<<<256, 256, 0, stream>>>(out, out_size,
                                               100.0f + (float)(ws_size >> 20));
    return;
  }

  convert_f32_bf16<<<2048, 256, 0, stream>>>(x, xb, 8192 * 768);
  convert_f32_bf16<<<16, 256, 0, stream>>>(b_attn, ba, 2304);
  convert_f32_bf16<<<8, 256, 0, stream>>>(b_proj, bp, 768);
  transpose_f32_bf16<<<dim3(72, 24), 256, 0, stream>>>(w_attn, WtA, 768, 2304);
  transpose_f32_bf16<<<dim3(24, 24), 256, 0, stream>>>(w_proj, WtP, 768, 768);

  gemm128<0><<<dim3(64, 18), 256, 0, stream>>>(xb, WtA, ba, Q, Kp, Vt, 768);
  attn_chunk<<<1920, 256, 0, stream>>>(Q, Kp, Vt, Y, part_o, part_l);
  attn_combine<<<dim3(24, 24), 256, 0, stream>>>(part_o, part_l, Y);
  gemm128<1><<<dim3(64, 6), 256, 0, stream>>>(Y, WtP, bp, out, nullptr, nullptr, 768);
}